// Round 1
// baseline (38995.218 us; speedup 1.0000x reference)
//
#include <hip/hip_runtime.h>
#include <math.h>

#define N_NODES 4096
#define WORDS   64
#define HID     256
#define VOCAB   50257
#define NCLASS  4
#define N_LEAF  2048
#define RNN_BLOCKS 512   // 2 blocks/CU on 256 CUs -> guaranteed co-resident (spin-wait safe)

// ---------------------------------------------------------------- init flags
__global__ void init_flags_kernel(int* __restrict__ flags) {
  int i = blockIdx.x * blockDim.x + threadIdx.x;
  if (i < N_NODES) flags[i] = 0;
}

// ---------------------------------------------------------------- transpose (R,C) -> (C,R); R multiple of 32
__global__ void transpose_kernel(const float* __restrict__ src, float* __restrict__ dst,
                                 int R, int C) {
  __shared__ float tile[32][33];
  int c0 = blockIdx.x * 32, r0 = blockIdx.y * 32;
  int tx = threadIdx.x, ty = threadIdx.y;
#pragma unroll
  for (int j = 0; j < 32; j += 8) {
    int c = c0 + tx, r = r0 + ty + j;
    if (c < C) tile[ty + j][tx] = src[(size_t)r * C + c];
  }
  __syncthreads();
#pragma unroll
  for (int j = 0; j < 32; j += 8) {
    int c = c0 + ty + j, r = r0 + tx;
    if (c < C) dst[(size_t)c * R + r] = tile[tx][ty + j];
  }
}

// ---------------------------------------------------------------- X[i,h] = sum_w E_T[tree[i,w], h]
__global__ void gather_x_kernel(const int* __restrict__ tree, const float* __restrict__ ET,
                                float* __restrict__ X, float* __restrict__ H) {
  int i = blockIdx.x;
  int h = threadIdx.x;
  __shared__ int vs[WORDS];
  if (h < WORDS) vs[h] = tree[i * WORDS + h];
  __syncthreads();
  float acc = 0.f;
#pragma unroll 8
  for (int w = 0; w < WORDS; ++w) acc += ET[(size_t)vs[w] * HID + h];
  X[i * HID + h] = acc;
  if (i == 0) H[h] = acc;   // node 0: h = X[0]
}

// ---------------------------------------------------------------- A = X @ W^T for 3 weights
// C[m,n] = sum_k X[m,k] * W[n,k].  64x64 tile, 256 threads, 4x4 per thread, BK=16.
__global__ void __launch_bounds__(256) gemm3_kernel(
    const float* __restrict__ X,
    const float* __restrict__ W0, const float* __restrict__ W1, const float* __restrict__ W2,
    float* __restrict__ A0, float* __restrict__ A1, float* __restrict__ A2) {
  const float* W = blockIdx.z == 0 ? W0 : (blockIdx.z == 1 ? W1 : W2);
  float*       A = blockIdx.z == 0 ? A0 : (blockIdx.z == 1 ? A1 : A2);
  __shared__ float Xs[16][65];
  __shared__ float Ws[16][65];
  int tid = threadIdx.x;
  int m0 = blockIdx.x * 64, n0 = blockIdx.y * 64;
  int tm = (tid / 16) * 4, tn = (tid % 16) * 4;
  int lm = tid >> 2, lk = (tid & 3) * 4;
  float acc[4][4];
#pragma unroll
  for (int a = 0; a < 4; ++a)
#pragma unroll
    for (int b = 0; b < 4; ++b) acc[a][b] = 0.f;

  for (int k0 = 0; k0 < HID; k0 += 16) {
    float4 xv = *(const float4*)(X + (size_t)(m0 + lm) * HID + k0 + lk);
    Xs[lk + 0][lm] = xv.x; Xs[lk + 1][lm] = xv.y; Xs[lk + 2][lm] = xv.z; Xs[lk + 3][lm] = xv.w;
    float4 wv = *(const float4*)(W + (size_t)(n0 + lm) * HID + k0 + lk);
    Ws[lk + 0][lm] = wv.x; Ws[lk + 1][lm] = wv.y; Ws[lk + 2][lm] = wv.z; Ws[lk + 3][lm] = wv.w;
    __syncthreads();
#pragma unroll
    for (int k = 0; k < 16; ++k) {
      float xm[4], wn[4];
#pragma unroll
      for (int u = 0; u < 4; ++u) { xm[u] = Xs[k][tm + u]; wn[u] = Ws[k][tn + u]; }
#pragma unroll
      for (int a = 0; a < 4; ++a)
#pragma unroll
        for (int b = 0; b < 4; ++b) acc[a][b] = fmaf(xm[a], wn[b], acc[a][b]);
    }
    __syncthreads();
  }
#pragma unroll
  for (int a = 0; a < 4; ++a)
#pragma unroll
    for (int b = 0; b < 4; ++b)
      A[(size_t)(m0 + tm + a) * HID + n0 + tn + b] = acc[a][b];
}

// ---------------------------------------------------------------- persistent wavefront GRU scan
__global__ void __launch_bounds__(256, 2) rnn_kernel(
    const float* __restrict__ Az, const float* __restrict__ Ar, const float* __restrict__ Ah,
    const float* __restrict__ UzT, const float* __restrict__ UrT, const float* __restrict__ UhT,
    const float* __restrict__ bz, const float* __restrict__ br, const float* __restrict__ bh,
    const int* __restrict__ edge, float* __restrict__ H, int* flags) {
  int h = threadIdx.x;
  __shared__ float phs[HID];
  __shared__ float rhs[HID];

  for (int i = blockIdx.x; i < N_NODES; i += RNN_BLOCKS) {
    if (i == 0) {
      // H row 0 was written by gather kernel (prior kernel on stream -> visible)
      if (h == 0)
        __hip_atomic_store(&flags[0], 1, __ATOMIC_RELEASE, __HIP_MEMORY_SCOPE_AGENT);
      continue;
    }
    int p = edge[2 * i];   // parent, p < i
    if (h == 0) {
      long spin = 0;
      while (__hip_atomic_load(&flags[p], __ATOMIC_ACQUIRE, __HIP_MEMORY_SCOPE_AGENT) == 0) {
        __builtin_amdgcn_s_sleep(1);
        if (++spin > (1L << 24)) break;   // deadlock escape hatch (should never trigger)
      }
    }
    __syncthreads();

    float phv = H[(size_t)p * HID + h];
    phs[h] = phv;
    __syncthreads();

    float zacc = Az[(size_t)i * HID + h] + bz[h];
    float racc = Ar[(size_t)i * HID + h] + br[h];
#pragma unroll 4
    for (int k = 0; k < HID; ++k) {
      float pk = phs[k];
      zacc = fmaf(UzT[k * HID + h], pk, zacc);
      racc = fmaf(UrT[k * HID + h], pk, racc);
    }
    float z = 1.f / (1.f + expf(-zacc));
    float r = 1.f / (1.f + expf(-racc));
    rhs[h] = r * phv;
    __syncthreads();

    float cacc = Ah[(size_t)i * HID + h] + bh[h];
#pragma unroll 4
    for (int k = 0; k < HID; ++k)
      cacc = fmaf(UhT[k * HID + h], rhs[k], cacc);
    float c = tanhf(cacc);
    float hnew = z * phv + (1.f - z) * c;

    H[(size_t)i * HID + h] = hnew;
    __threadfence();
    __syncthreads();
    if (h == 0)
      __hip_atomic_store(&flags[i], 1, __ATOMIC_RELEASE, __HIP_MEMORY_SCOPE_AGENT);
  }
}

// ---------------------------------------------------------------- leaf max partial (64 blocks x 32 leaves)
__global__ void leafmax_kernel(const float* __restrict__ H, const int* __restrict__ leafs,
                               float* __restrict__ partial) {
  int b = blockIdx.x;
  int h = threadIdx.x;
  float m = -INFINITY;
#pragma unroll 4
  for (int j = 0; j < N_LEAF / 64; ++j) {
    int node = leafs[b * (N_LEAF / 64) + j];
    m = fmaxf(m, H[(size_t)node * HID + h]);
  }
  partial[b * HID + h] = m;
}

// ---------------------------------------------------------------- final: reduce partials, W_out, softmax, loss
__global__ void final_kernel(const float* __restrict__ partial, const float* __restrict__ W_out,
                             const float* __restrict__ b_out, const float* __restrict__ y,
                             float* __restrict__ out) {
  int h = threadIdx.x;
  float m = -INFINITY;
#pragma unroll 8
  for (int b = 0; b < 64; ++b) m = fmaxf(m, partial[b * HID + h]);
  __shared__ float fs[HID];
  __shared__ float red[HID];
  __shared__ float logit[NCLASS];
  fs[h] = m;
  __syncthreads();
  for (int c = 0; c < NCLASS; ++c) {
    red[h] = W_out[c * HID + h] * fs[h];
    __syncthreads();
    for (int s = HID / 2; s > 0; s >>= 1) {
      if (h < s) red[h] += red[h + s];
      __syncthreads();
    }
    if (h == 0) logit[c] = red[0] + b_out[c];
    __syncthreads();
  }
  if (h == 0) {
    float mx = logit[0];
    for (int c = 1; c < NCLASS; ++c) mx = fmaxf(mx, logit[c]);
    float e[NCLASS], s = 0.f;
    for (int c = 0; c < NCLASS; ++c) { e[c] = expf(logit[c] - mx); s += e[c]; }
    float loss = 0.f;
    for (int c = 0; c < NCLASS; ++c) {
      float p = e[c] / s;
      out[c] = p;
      float d = y[c] - p;
      loss += d * d;
    }
    out[NCLASS] = loss;
  }
}

// ---------------------------------------------------------------- launch
extern "C" void kernel_launch(void* const* d_in, const int* in_sizes, int n_in,
                              void* d_out, int out_size, void* d_ws, size_t ws_size,
                              hipStream_t stream) {
  const int*   tree = (const int*)d_in[0];
  const int*   edge = (const int*)d_in[1];
  const int*   leaf = (const int*)d_in[2];
  const float* y    = (const float*)d_in[3];
  const float* E    = (const float*)d_in[4];
  const float* Wz   = (const float*)d_in[5];
  const float* Uz   = (const float*)d_in[6];
  const float* bz   = (const float*)d_in[7];
  const float* Wr   = (const float*)d_in[8];
  const float* Ur   = (const float*)d_in[9];
  const float* br   = (const float*)d_in[10];
  const float* Wh   = (const float*)d_in[11];
  const float* Uh   = (const float*)d_in[12];
  const float* bh   = (const float*)d_in[13];
  const float* Wout = (const float*)d_in[14];
  const float* bout = (const float*)d_in[15];
  float* out = (float*)d_out;

  float* ws = (float*)d_ws;
  size_t off = 0;
  float* ET  = ws + off; off += (size_t)VOCAB * HID;     // 12,865,792 f
  float* UzT = ws + off; off += (size_t)HID * HID;
  float* UrT = ws + off; off += (size_t)HID * HID;
  float* UhT = ws + off; off += (size_t)HID * HID;
  float* X   = ws + off; off += (size_t)N_NODES * HID;
  float* Az  = ws + off; off += (size_t)N_NODES * HID;
  float* Ar  = ws + off; off += (size_t)N_NODES * HID;
  float* Ah  = ws + off; off += (size_t)N_NODES * HID;
  float* H   = ws + off; off += (size_t)N_NODES * HID;
  float* partial = ws + off; off += 64 * HID;
  int*   flags   = (int*)(ws + off); off += N_NODES;
  // total ~73.3 MB of ws

  init_flags_kernel<<<(N_NODES + 255) / 256, 256, 0, stream>>>(flags);
  transpose_kernel<<<dim3((VOCAB + 31) / 32, HID / 32), dim3(32, 8), 0, stream>>>(E, ET, HID, VOCAB);
  transpose_kernel<<<dim3(HID / 32, HID / 32), dim3(32, 8), 0, stream>>>(Uz, UzT, HID, HID);
  transpose_kernel<<<dim3(HID / 32, HID / 32), dim3(32, 8), 0, stream>>>(Ur, UrT, HID, HID);
  transpose_kernel<<<dim3(HID / 32, HID / 32), dim3(32, 8), 0, stream>>>(Uh, UhT, HID, HID);
  gather_x_kernel<<<N_NODES, HID, 0, stream>>>(tree, ET, X, H);
  gemm3_kernel<<<dim3(N_NODES / 64, HID / 64, 3), 256, 0, stream>>>(X, Wz, Wr, Wh, Az, Ar, Ah);
  rnn_kernel<<<RNN_BLOCKS, HID, 0, stream>>>(Az, Ar, Ah, UzT, UrT, UhT, bz, br, bh, edge, H, flags);
  leafmax_kernel<<<64, HID, 0, stream>>>(H, leaf, partial);
  final_kernel<<<1, HID, 0, stream>>>(partial, Wout, bout, y, out);
}

// Round 2
// 1742.448 us; speedup vs baseline: 22.3796x; 22.3796x over previous
//
#include <hip/hip_runtime.h>
#include <math.h>

#define N_NODES 4096
#define WORDS   64
#define HID     256
#define VOCAB   50257
#define NCLASS  4
#define N_LEAF  2048
#define RNN_BLOCKS 256   // 1 block/CU (16 waves) -> all resident, spin-wait safe
#define FLAG_STRIDE 16   // one 64B line per flag: no coherence-point line contention

// ---------------------------------------------------------------- init flags
__global__ void init_flags_kernel(int* __restrict__ flags) {
  int i = blockIdx.x * blockDim.x + threadIdx.x;
  if (i < N_NODES * FLAG_STRIDE) flags[i] = 0;
}

// ---------------------------------------------------------------- transpose (R,C) -> (C,R); R multiple of 32
__global__ void transpose_kernel(const float* __restrict__ src, float* __restrict__ dst,
                                 int R, int C) {
  __shared__ float tile[32][33];
  int c0 = blockIdx.x * 32, r0 = blockIdx.y * 32;
  int tx = threadIdx.x, ty = threadIdx.y;
#pragma unroll
  for (int j = 0; j < 32; j += 8) {
    int c = c0 + tx, r = r0 + ty + j;
    if (c < C) tile[ty + j][tx] = src[(size_t)r * C + c];
  }
  __syncthreads();
#pragma unroll
  for (int j = 0; j < 32; j += 8) {
    int c = c0 + ty + j, r = r0 + tx;
    if (c < C) dst[(size_t)c * R + r] = tile[tx][ty + j];
  }
}

// ---------------------------------------------------------------- X[i,h] = sum_w E_T[tree[i,w], h]
__global__ void gather_x_kernel(const int* __restrict__ tree, const float* __restrict__ ET,
                                float* __restrict__ X, float* __restrict__ H) {
  int i = blockIdx.x;
  int h = threadIdx.x;
  __shared__ int vs[WORDS];
  if (h < WORDS) vs[h] = tree[i * WORDS + h];
  __syncthreads();
  float acc = 0.f;
#pragma unroll 8
  for (int w = 0; w < WORDS; ++w) acc += ET[(size_t)vs[w] * HID + h];
  X[i * HID + h] = acc;
  if (i == 0) H[h] = acc;   // node 0: h = X[0]  (kernel-end flush -> visible at coherence point)
}

// ---------------------------------------------------------------- A = X @ W^T for 3 weights
__global__ void __launch_bounds__(256) gemm3_kernel(
    const float* __restrict__ X,
    const float* __restrict__ W0, const float* __restrict__ W1, const float* __restrict__ W2,
    float* __restrict__ A0, float* __restrict__ A1, float* __restrict__ A2) {
  const float* W = blockIdx.z == 0 ? W0 : (blockIdx.z == 1 ? W1 : W2);
  float*       A = blockIdx.z == 0 ? A0 : (blockIdx.z == 1 ? A1 : A2);
  __shared__ float Xs[16][65];
  __shared__ float Ws[16][65];
  int tid = threadIdx.x;
  int m0 = blockIdx.x * 64, n0 = blockIdx.y * 64;
  int tm = (tid / 16) * 4, tn = (tid % 16) * 4;
  int lm = tid >> 2, lk = (tid & 3) * 4;
  float acc[4][4];
#pragma unroll
  for (int a = 0; a < 4; ++a)
#pragma unroll
    for (int b = 0; b < 4; ++b) acc[a][b] = 0.f;

  for (int k0 = 0; k0 < HID; k0 += 16) {
    float4 xv = *(const float4*)(X + (size_t)(m0 + lm) * HID + k0 + lk);
    Xs[lk + 0][lm] = xv.x; Xs[lk + 1][lm] = xv.y; Xs[lk + 2][lm] = xv.z; Xs[lk + 3][lm] = xv.w;
    float4 wv = *(const float4*)(W + (size_t)(n0 + lm) * HID + k0 + lk);
    Ws[lk + 0][lm] = wv.x; Ws[lk + 1][lm] = wv.y; Ws[lk + 2][lm] = wv.z; Ws[lk + 3][lm] = wv.w;
    __syncthreads();
#pragma unroll
    for (int k = 0; k < 16; ++k) {
      float xm[4], wn[4];
#pragma unroll
      for (int u = 0; u < 4; ++u) { xm[u] = Xs[k][tm + u]; wn[u] = Ws[k][tn + u]; }
#pragma unroll
      for (int a = 0; a < 4; ++a)
#pragma unroll
        for (int b = 0; b < 4; ++b) acc[a][b] = fmaf(xm[a], wn[b], acc[a][b]);
    }
    __syncthreads();
  }
#pragma unroll
  for (int a = 0; a < 4; ++a)
#pragma unroll
    for (int b = 0; b < 4; ++b)
      A[(size_t)(m0 + tm + a) * HID + n0 + tn + b] = acc[a][b];
}

// ---------------------------------------------------------------- persistent wavefront GRU scan
// 1024 threads/node: h = tid&255, k-slice = tid>>8 (4 slices of 64).
// Handoff protocol: relaxed AGENT atomics only (sc0|sc1 write/read-through, NO
// buffer_wbl2/buffer_inv cache maintenance). Ordering: H stores -> s_waitcnt
// vmcnt(0) (per storing wave) -> __syncthreads -> flag store. Any consumer that
// observes flag=1 at the coherence point sees the ACKed H row.
__global__ void __launch_bounds__(1024, 4) rnn_kernel(
    const float* __restrict__ Az, const float* __restrict__ Ar, const float* __restrict__ Ah,
    const float* __restrict__ UzT, const float* __restrict__ UrT, const float* __restrict__ UhT,
    const float* __restrict__ bz, const float* __restrict__ br, const float* __restrict__ bh,
    const int* __restrict__ edge, float* __restrict__ H, int* flags) {
  const int tid = threadIdx.x;
  const int h   = tid & (HID - 1);
  const int ks  = tid >> 8;        // 0..3
  const int k0  = ks * 64;
  __shared__ float phs[HID];
  __shared__ float part_a[4][HID];
  __shared__ float part_b[4][HID];
  __shared__ float zs[HID];
  __shared__ float rhs[HID];

  for (int i = blockIdx.x; i < N_NODES; i += RNN_BLOCKS) {
    if (i == 0) {
      if (tid == 0)
        __hip_atomic_store(&flags[0], 1, __ATOMIC_RELAXED, __HIP_MEMORY_SCOPE_AGENT);
      continue;
    }
    const int p = edge[2 * i];   // parent, p < i
    if (tid == 0) {
      long spin = 0;
      while (__hip_atomic_load(&flags[(size_t)p * FLAG_STRIDE], __ATOMIC_RELAXED,
                               __HIP_MEMORY_SCOPE_AGENT) == 0) {
        __builtin_amdgcn_s_sleep(1);
        if (++spin > (1L << 21)) break;   // escape hatch (should never trigger)
      }
    }
    __syncthreads();

    if (ks == 0)
      phs[h] = __hip_atomic_load(&H[(size_t)p * HID + h], __ATOMIC_RELAXED,
                                 __HIP_MEMORY_SCOPE_AGENT);
    __syncthreads();

    // phase 1: partial U_z@ph, U_r@ph over k-slice
    {
      float zp = 0.f, rp = 0.f;
      const float* uz = UzT + (size_t)k0 * HID + h;
      const float* ur = UrT + (size_t)k0 * HID + h;
#pragma unroll 8
      for (int k = 0; k < 64; ++k) {
        float pk = phs[k0 + k];
        zp = fmaf(uz[(size_t)k * HID], pk, zp);
        rp = fmaf(ur[(size_t)k * HID], pk, rp);
      }
      part_a[ks][h] = zp;
      part_b[ks][h] = rp;
    }
    __syncthreads();

    if (ks == 0) {
      float za = Az[(size_t)i * HID + h] + bz[h]
               + part_a[0][h] + part_a[1][h] + part_a[2][h] + part_a[3][h];
      float ra = Ar[(size_t)i * HID + h] + br[h]
               + part_b[0][h] + part_b[1][h] + part_b[2][h] + part_b[3][h];
      float z = 1.f / (1.f + expf(-za));
      float r = 1.f / (1.f + expf(-ra));
      zs[h]  = z;
      rhs[h] = r * phs[h];
    }
    __syncthreads();

    // phase 2: partial U_h@(r*ph)
    {
      float cp = 0.f;
      const float* uh = UhT + (size_t)k0 * HID + h;
#pragma unroll 8
      for (int k = 0; k < 64; ++k)
        cp = fmaf(uh[(size_t)k * HID], rhs[k0 + k], cp);
      part_a[ks][h] = cp;
    }
    __syncthreads();

    if (ks == 0) {
      float ca = Ah[(size_t)i * HID + h] + bh[h]
               + part_a[0][h] + part_a[1][h] + part_a[2][h] + part_a[3][h];
      float c  = tanhf(ca);
      float z  = zs[h];
      float hn = fmaf(z, phs[h], (1.f - z) * c);
      __hip_atomic_store(&H[(size_t)i * HID + h], hn, __ATOMIC_RELAXED,
                         __HIP_MEMORY_SCOPE_AGENT);
    }
    __builtin_amdgcn_s_waitcnt(0);   // drain this wave's store acks
    __syncthreads();                  // all waves past their waitcnt
    if (tid == 0) {
      __atomic_signal_fence(__ATOMIC_SEQ_CST);
      __hip_atomic_store(&flags[(size_t)i * FLAG_STRIDE], 1, __ATOMIC_RELAXED,
                         __HIP_MEMORY_SCOPE_AGENT);
    }
  }
}

// ---------------------------------------------------------------- leaf max partial (64 blocks x 32 leaves)
__global__ void leafmax_kernel(const float* __restrict__ H, const int* __restrict__ leafs,
                               float* __restrict__ partial) {
  int b = blockIdx.x;
  int h = threadIdx.x;
  float m = -INFINITY;
#pragma unroll 4
  for (int j = 0; j < N_LEAF / 64; ++j) {
    int node = leafs[b * (N_LEAF / 64) + j];
    m = fmaxf(m, H[(size_t)node * HID + h]);
  }
  partial[b * HID + h] = m;
}

// ---------------------------------------------------------------- final: reduce partials, W_out, softmax, loss
__global__ void final_kernel(const float* __restrict__ partial, const float* __restrict__ W_out,
                             const float* __restrict__ b_out, const float* __restrict__ y,
                             float* __restrict__ out) {
  int h = threadIdx.x;
  float m = -INFINITY;
#pragma unroll 8
  for (int b = 0; b < 64; ++b) m = fmaxf(m, partial[b * HID + h]);
  __shared__ float fs[HID];
  __shared__ float red[HID];
  __shared__ float logit[NCLASS];
  fs[h] = m;
  __syncthreads();
  for (int c = 0; c < NCLASS; ++c) {
    red[h] = W_out[c * HID + h] * fs[h];
    __syncthreads();
    for (int s = HID / 2; s > 0; s >>= 1) {
      if (h < s) red[h] += red[h + s];
      __syncthreads();
    }
    if (h == 0) logit[c] = red[0] + b_out[c];
    __syncthreads();
  }
  if (h == 0) {
    float mx = logit[0];
    for (int c = 1; c < NCLASS; ++c) mx = fmaxf(mx, logit[c]);
    float e[NCLASS], s = 0.f;
    for (int c = 0; c < NCLASS; ++c) { e[c] = expf(logit[c] - mx); s += e[c]; }
    float loss = 0.f;
    for (int c = 0; c < NCLASS; ++c) {
      float p = e[c] / s;
      out[c] = p;
      float d = y[c] - p;
      loss += d * d;
    }
    out[NCLASS] = loss;
  }
}

// ---------------------------------------------------------------- launch
extern "C" void kernel_launch(void* const* d_in, const int* in_sizes, int n_in,
                              void* d_out, int out_size, void* d_ws, size_t ws_size,
                              hipStream_t stream) {
  const int*   tree = (const int*)d_in[0];
  const int*   edge = (const int*)d_in[1];
  const int*   leaf = (const int*)d_in[2];
  const float* y    = (const float*)d_in[3];
  const float* E    = (const float*)d_in[4];
  const float* Wz   = (const float*)d_in[5];
  const float* Uz   = (const float*)d_in[6];
  const float* bz   = (const float*)d_in[7];
  const float* Wr   = (const float*)d_in[8];
  const float* Ur   = (const float*)d_in[9];
  const float* br   = (const float*)d_in[10];
  const float* Wh   = (const float*)d_in[11];
  const float* Uh   = (const float*)d_in[12];
  const float* bh   = (const float*)d_in[13];
  const float* Wout = (const float*)d_in[14];
  const float* bout = (const float*)d_in[15];
  float* out = (float*)d_out;

  float* ws = (float*)d_ws;
  size_t off = 0;
  float* ET  = ws + off; off += (size_t)VOCAB * HID;
  float* UzT = ws + off; off += (size_t)HID * HID;
  float* UrT = ws + off; off += (size_t)HID * HID;
  float* UhT = ws + off; off += (size_t)HID * HID;
  float* X   = ws + off; off += (size_t)N_NODES * HID;
  float* Az  = ws + off; off += (size_t)N_NODES * HID;
  float* Ar  = ws + off; off += (size_t)N_NODES * HID;
  float* Ah  = ws + off; off += (size_t)N_NODES * HID;
  float* H   = ws + off; off += (size_t)N_NODES * HID;
  float* partial = ws + off; off += 64 * HID;
  int*   flags   = (int*)(ws + off); off += N_NODES * FLAG_STRIDE;

  init_flags_kernel<<<(N_NODES * FLAG_STRIDE + 255) / 256, 256, 0, stream>>>(flags);
  transpose_kernel<<<dim3((VOCAB + 31) / 32, HID / 32), dim3(32, 8), 0, stream>>>(E, ET, HID, VOCAB);
  transpose_kernel<<<dim3(HID / 32, HID / 32), dim3(32, 8), 0, stream>>>(Uz, UzT, HID, HID);
  transpose_kernel<<<dim3(HID / 32, HID / 32), dim3(32, 8), 0, stream>>>(Ur, UrT, HID, HID);
  transpose_kernel<<<dim3(HID / 32, HID / 32), dim3(32, 8), 0, stream>>>(Uh, UhT, HID, HID);
  gather_x_kernel<<<N_NODES, HID, 0, stream>>>(tree, ET, X, H);
  gemm3_kernel<<<dim3(N_NODES / 64, HID / 64, 3), 256, 0, stream>>>(X, Wz, Wr, Wh, Az, Ar, Ah);
  rnn_kernel<<<RNN_BLOCKS, 1024, 0, stream>>>(Az, Ar, Ah, UzT, UrT, UhT, bz, br, bh, edge, H, flags);
  leafmax_kernel<<<64, HID, 0, stream>>>(H, leaf, partial);
  final_kernel<<<1, HID, 0, stream>>>(partial, Wout, bout, y, out);
}

// Round 3
// 978.832 us; speedup vs baseline: 39.8385x; 1.7801x over previous
//
#include <hip/hip_runtime.h>
#include <math.h>

#define N_NODES 4096
#define WORDS   64
#define HID     256
#define VOCAB   50257
#define NCLASS  4
#define N_LEAF  2048
#define RNN_BLOCKS 256   // 1 block/CU (16 waves) -> all resident, spin-wait safe
#define FLAG_STRIDE 16   // one 64B line per flag

typedef _Float16 half2_t __attribute__((ext_vector_type(2)));

__device__ __forceinline__ float dot2f(half2_t a, half2_t b, float c) {
#if __has_builtin(__builtin_amdgcn_fdot2)
  return __builtin_amdgcn_fdot2(a, b, c, false);   // v_dot2_f32_f16
#else
  return c + (float)a.x * (float)b.x + (float)a.y * (float)b.y;
#endif
}

// ---------------------------------------------------------------- init flags
__global__ void init_flags_kernel(int* __restrict__ flags) {
  int i = blockIdx.x * blockDim.x + threadIdx.x;
  if (i < N_NODES * FLAG_STRIDE) flags[i] = 0;
}

// ---------------------------------------------------------------- transpose (R,C) -> (C,R); for E only
__global__ void transpose_kernel(const float* __restrict__ src, float* __restrict__ dst,
                                 int R, int C) {
  __shared__ float tile[32][33];
  int c0 = blockIdx.x * 32, r0 = blockIdx.y * 32;
  int tx = threadIdx.x, ty = threadIdx.y;
#pragma unroll
  for (int j = 0; j < 32; j += 8) {
    int c = c0 + tx, r = r0 + ty + j;
    if (c < C) tile[ty + j][tx] = src[(size_t)r * C + c];
  }
  __syncthreads();
#pragma unroll
  for (int j = 0; j < 32; j += 8) {
    int c = c0 + ty + j, r = r0 + tx;
    if (c < C) dst[(size_t)c * R + r] = tile[tx][ty + j];
  }
}

// ---------------------------------------------------------------- pack U -> half2, layout Upk[(m*4+ks)*8192 + j*256 + h]
// pair (k = ks*64+2j, ks*64+2j+1) of U_m[h][k]
__global__ void __launch_bounds__(256) pack_u_kernel(
    const float* __restrict__ Uz, const float* __restrict__ Ur, const float* __restrict__ Uh,
    half2_t* __restrict__ Upk) {
  __shared__ float tile[64][259];   // 259: bank-conflict-free column reads
  int m = blockIdx.x >> 2, g = blockIdx.x & 3;
  const float* U = m == 0 ? Uz : (m == 1 ? Ur : Uh);
  int t = threadIdx.x;
  for (int r = 0; r < 64; ++r) tile[r][t] = U[(size_t)(g * 64 + r) * 256 + t];
  __syncthreads();
#pragma unroll
  for (int it = 0; it < 32; ++it) {
    int e = it * 256 + t;
    int hl = e & 63, kj = e >> 6, ks = kj >> 5, j = kj & 31;
    half2_t v;
    v.x = (_Float16)tile[hl][ks * 64 + 2 * j];
    v.y = (_Float16)tile[hl][ks * 64 + 2 * j + 1];
    Upk[(size_t)(m * 4 + ks) * 8192 + j * 256 + (g * 64 + hl)] = v;
  }
}

// ---------------------------------------------------------------- X[i,h] = sum_w E_T[tree[i,w], h]
__global__ void gather_x_kernel(const int* __restrict__ tree, const float* __restrict__ ET,
                                float* __restrict__ X, float* __restrict__ H) {
  int i = blockIdx.x;
  int h = threadIdx.x;
  __shared__ int vs[WORDS];
  if (h < WORDS) vs[h] = tree[i * WORDS + h];
  __syncthreads();
  float acc = 0.f;
#pragma unroll 8
  for (int w = 0; w < WORDS; ++w) acc += ET[(size_t)vs[w] * HID + h];
  X[i * HID + h] = acc;
  if (i == 0) H[h] = acc;   // node 0: h = X[0]
}

// ---------------------------------------------------------------- A = X @ W^T for 3 weights
__global__ void __launch_bounds__(256) gemm3_kernel(
    const float* __restrict__ X,
    const float* __restrict__ W0, const float* __restrict__ W1, const float* __restrict__ W2,
    float* __restrict__ A0, float* __restrict__ A1, float* __restrict__ A2) {
  const float* W = blockIdx.z == 0 ? W0 : (blockIdx.z == 1 ? W1 : W2);
  float*       A = blockIdx.z == 0 ? A0 : (blockIdx.z == 1 ? A1 : A2);
  __shared__ float Xs[16][65];
  __shared__ float Ws[16][65];
  int tid = threadIdx.x;
  int m0 = blockIdx.x * 64, n0 = blockIdx.y * 64;
  int tm = (tid / 16) * 4, tn = (tid % 16) * 4;
  int lm = tid >> 2, lk = (tid & 3) * 4;
  float acc[4][4];
#pragma unroll
  for (int a = 0; a < 4; ++a)
#pragma unroll
    for (int b = 0; b < 4; ++b) acc[a][b] = 0.f;

  for (int k0 = 0; k0 < HID; k0 += 16) {
    float4 xv = *(const float4*)(X + (size_t)(m0 + lm) * HID + k0 + lk);
    Xs[lk + 0][lm] = xv.x; Xs[lk + 1][lm] = xv.y; Xs[lk + 2][lm] = xv.z; Xs[lk + 3][lm] = xv.w;
    float4 wv = *(const float4*)(W + (size_t)(n0 + lm) * HID + k0 + lk);
    Ws[lk + 0][lm] = wv.x; Ws[lk + 1][lm] = wv.y; Ws[lk + 2][lm] = wv.z; Ws[lk + 3][lm] = wv.w;
    __syncthreads();
#pragma unroll
    for (int k = 0; k < 16; ++k) {
      float xm[4], wn[4];
#pragma unroll
      for (int u = 0; u < 4; ++u) { xm[u] = Xs[k][tm + u]; wn[u] = Ws[k][tn + u]; }
#pragma unroll
      for (int a = 0; a < 4; ++a)
#pragma unroll
        for (int b = 0; b < 4; ++b) acc[a][b] = fmaf(xm[a], wn[b], acc[a][b]);
    }
    __syncthreads();
  }
#pragma unroll
  for (int a = 0; a < 4; ++a)
#pragma unroll
    for (int b = 0; b < 4; ++b)
      A[(size_t)(m0 + tm + a) * HID + n0 + tn + b] = acc[a][b];
}

// ---------------------------------------------------------------- persistent wavefront GRU scan, U pinned in registers
// thread (h = tid&255, ks = tid>>8): holds Uz/Ur/Uh[h][ks*64 .. +63] as 3x32 half2 regs (96 VGPRs).
// Per node: zero global U traffic; matvecs via v_dot2_f32_f16 against LDS-broadcast packed ph / r*ph.
// Handoff: relaxed AGENT atomics (no cache maintenance); H stores -> s_waitcnt 0 -> barrier -> flag.
__global__ void __launch_bounds__(1024, 4) rnn_kernel(
    const float* __restrict__ Az, const float* __restrict__ Ar, const float* __restrict__ Ah,
    const half2_t* __restrict__ Upk,
    const float* __restrict__ bz, const float* __restrict__ br, const float* __restrict__ bh,
    const int* __restrict__ edge, float* __restrict__ H, int* flags) {
  const int tid = threadIdx.x;
  const int h   = tid & (HID - 1);
  const int ks  = tid >> 8;        // 0..3
  __shared__ half2_t php[HID / 2];
  __shared__ half2_t rhp[HID / 2];
  __shared__ float part_a[4 * HID];
  __shared__ float part_b[4 * HID];

  half2_t uz[32], ur[32], uh[32];
  {
    const half2_t* bp = Upk + (size_t)ks * 8192 + h;
#pragma unroll
    for (int j = 0; j < 32; ++j) {
      uz[j] = bp[j * 256];
      ur[j] = bp[32768 + j * 256];
      uh[j] = bp[65536 + j * 256];
    }
  }
  float bzr = 0.f, brr = 0.f, bhr = 0.f;
  if (ks == 0) { bzr = bz[h]; brr = br[h]; bhr = bh[h]; }

  for (int i = blockIdx.x; i < N_NODES; i += RNN_BLOCKS) {
    if (i == 0) {
      if (tid == 0)
        __hip_atomic_store(&flags[0], 1, __ATOMIC_RELAXED, __HIP_MEMORY_SCOPE_AGENT);
      continue;
    }
    const int p = edge[2 * i];   // parent, p < i
    float az = 0.f, ar = 0.f, ah = 0.f;
    if (ks == 0) {               // issue before the wait; completes during spin
      az = Az[(size_t)i * HID + h];
      ar = Ar[(size_t)i * HID + h];
      ah = Ah[(size_t)i * HID + h];
    }
    if (tid == 0) {
      long spin = 0;
      while (__hip_atomic_load(&flags[(size_t)p * FLAG_STRIDE], __ATOMIC_RELAXED,
                               __HIP_MEMORY_SCOPE_AGENT) == 0) {
        __builtin_amdgcn_s_sleep(1);
        if (++spin > (1L << 22)) break;   // escape hatch (should never trigger)
      }
    }
    __syncthreads();

    float phv = 0.f;
    if (ks == 0) {
      phv = __hip_atomic_load(&H[(size_t)p * HID + h], __ATOMIC_RELAXED,
                              __HIP_MEMORY_SCOPE_AGENT);
      float nb = __shfl_xor(phv, 1, 64);
      if ((h & 1) == 0) {
        half2_t v; v.x = (_Float16)phv; v.y = (_Float16)nb;
        php[h >> 1] = v;
      }
    }
    __syncthreads();

    // phase 1: z,r partial dots over this thread's k-slice (registers only)
    float zacc = 0.f, racc = 0.f;
#pragma unroll
    for (int j = 0; j < 32; ++j) {
      half2_t ph2 = php[(ks << 5) + j];   // wave-broadcast LDS read
      zacc = dot2f(uz[j], ph2, zacc);
      racc = dot2f(ur[j], ph2, racc);
    }
    part_a[ks * HID + h] = zacc;
    part_b[ks * HID + h] = racc;
    __syncthreads();

    float z = 0.f;
    if (ks == 0) {
      float za = az + bzr + part_a[h] + part_a[HID + h] + part_a[2 * HID + h] + part_a[3 * HID + h];
      float ra = ar + brr + part_b[h] + part_b[HID + h] + part_b[2 * HID + h] + part_b[3 * HID + h];
      z = 1.f / (1.f + expf(-za));
      float r = 1.f / (1.f + expf(-ra));
      float rh = r * phv;
      float nb = __shfl_xor(rh, 1, 64);
      if ((h & 1) == 0) {
        half2_t v; v.x = (_Float16)rh; v.y = (_Float16)nb;
        rhp[h >> 1] = v;
      }
    }
    __syncthreads();

    // phase 2: c partial dots
    float cacc = 0.f;
#pragma unroll
    for (int j = 0; j < 32; ++j)
      cacc = dot2f(uh[j], rhp[(ks << 5) + j], cacc);
    part_a[ks * HID + h] = cacc;
    __syncthreads();

    if (ks == 0) {
      float ca = ah + bhr + part_a[h] + part_a[HID + h] + part_a[2 * HID + h] + part_a[3 * HID + h];
      float c  = tanhf(ca);
      float hn = fmaf(z, phv, (1.f - z) * c);
      __hip_atomic_store(&H[(size_t)i * HID + h], hn, __ATOMIC_RELAXED,
                         __HIP_MEMORY_SCOPE_AGENT);
    }
    __builtin_amdgcn_s_waitcnt(0);   // drain this wave's store acks
    __syncthreads();                  // all waves past their waitcnt
    if (tid == 0)
      __hip_atomic_store(&flags[(size_t)i * FLAG_STRIDE], 1, __ATOMIC_RELAXED,
                         __HIP_MEMORY_SCOPE_AGENT);
  }
}

// ---------------------------------------------------------------- leaf max partial (64 blocks x 32 leaves)
__global__ void leafmax_kernel(const float* __restrict__ H, const int* __restrict__ leafs,
                               float* __restrict__ partial) {
  int b = blockIdx.x;
  int h = threadIdx.x;
  float m = -INFINITY;
#pragma unroll 4
  for (int j = 0; j < N_LEAF / 64; ++j) {
    int node = leafs[b * (N_LEAF / 64) + j];
    m = fmaxf(m, H[(size_t)node * HID + h]);
  }
  partial[b * HID + h] = m;
}

// ---------------------------------------------------------------- final: reduce partials, W_out, softmax, loss
__global__ void final_kernel(const float* __restrict__ partial, const float* __restrict__ W_out,
                             const float* __restrict__ b_out, const float* __restrict__ y,
                             float* __restrict__ out) {
  int h = threadIdx.x;
  float m = -INFINITY;
#pragma unroll 8
  for (int b = 0; b < 64; ++b) m = fmaxf(m, partial[b * HID + h]);
  __shared__ float fs[HID];
  __shared__ float red[HID];
  __shared__ float logit[NCLASS];
  fs[h] = m;
  __syncthreads();
  for (int c = 0; c < NCLASS; ++c) {
    red[h] = W_out[c * HID + h] * fs[h];
    __syncthreads();
    for (int s = HID / 2; s > 0; s >>= 1) {
      if (h < s) red[h] += red[h + s];
      __syncthreads();
    }
    if (h == 0) logit[c] = red[0] + b_out[c];
    __syncthreads();
  }
  if (h == 0) {
    float mx = logit[0];
    for (int c = 1; c < NCLASS; ++c) mx = fmaxf(mx, logit[c]);
    float e[NCLASS], s = 0.f;
    for (int c = 0; c < NCLASS; ++c) { e[c] = expf(logit[c] - mx); s += e[c]; }
    float loss = 0.f;
    for (int c = 0; c < NCLASS; ++c) {
      float p = e[c] / s;
      out[c] = p;
      float d = y[c] - p;
      loss += d * d;
    }
    out[NCLASS] = loss;
  }
}

// ---------------------------------------------------------------- launch
extern "C" void kernel_launch(void* const* d_in, const int* in_sizes, int n_in,
                              void* d_out, int out_size, void* d_ws, size_t ws_size,
                              hipStream_t stream) {
  const int*   tree = (const int*)d_in[0];
  const int*   edge = (const int*)d_in[1];
  const int*   leaf = (const int*)d_in[2];
  const float* y    = (const float*)d_in[3];
  const float* E    = (const float*)d_in[4];
  const float* Wz   = (const float*)d_in[5];
  const float* Uz   = (const float*)d_in[6];
  const float* bz   = (const float*)d_in[7];
  const float* Wr   = (const float*)d_in[8];
  const float* Ur   = (const float*)d_in[9];
  const float* br   = (const float*)d_in[10];
  const float* Wh   = (const float*)d_in[11];
  const float* Uh   = (const float*)d_in[12];
  const float* bh   = (const float*)d_in[13];
  const float* Wout = (const float*)d_in[14];
  const float* bout = (const float*)d_in[15];
  float* out = (float*)d_out;

  float* ws = (float*)d_ws;
  size_t off = 0;
  float*   ET  = ws + off; off += (size_t)VOCAB * HID;
  half2_t* Upk = (half2_t*)(ws + off); off += 3 * 4 * 8192;   // 98304 half2 = 49152 floats
  float* X   = ws + off; off += (size_t)N_NODES * HID;
  float* Az  = ws + off; off += (size_t)N_NODES * HID;
  float* Ar  = ws + off; off += (size_t)N_NODES * HID;
  float* Ah  = ws + off; off += (size_t)N_NODES * HID;
  float* H   = ws + off; off += (size_t)N_NODES * HID;
  float* partial = ws + off; off += 64 * HID;
  int*   flags   = (int*)(ws + off); off += N_NODES * FLAG_STRIDE;

  init_flags_kernel<<<(N_NODES * FLAG_STRIDE + 255) / 256, 256, 0, stream>>>(flags);
  transpose_kernel<<<dim3((VOCAB + 31) / 32, HID / 32), dim3(32, 8), 0, stream>>>(E, ET, HID, VOCAB);
  pack_u_kernel<<<12, 256, 0, stream>>>(Uz, Ur, Uh, Upk);
  gather_x_kernel<<<N_NODES, HID, 0, stream>>>(tree, ET, X, H);
  gemm3_kernel<<<dim3(N_NODES / 64, HID / 64, 3), 256, 0, stream>>>(X, Wz, Wr, Wh, Az, Ar, Ah);
  rnn_kernel<<<RNN_BLOCKS, 1024, 0, stream>>>(Az, Ar, Ah, Upk, bz, br, bh, edge, H, flags);
  leafmax_kernel<<<64, HID, 0, stream>>>(H, leaf, partial);
  final_kernel<<<1, HID, 0, stream>>>(partial, Wout, bout, y, out);
}